// Round 3
// baseline (250.253 us; speedup 1.0000x reference)
//
#include <hip/hip_runtime.h>

// norm_conv: im2col(3x3 reflect) -> row-normalize -> GEMM[576x64], fused.
// Design: out = (patches@W - mean*colsum(W)) * inv_std.
//  - kernel 1: pre-pack W (fp32->bf16) into per-lane MFMA fragment layout in ws.
//  - kernel 2: 256 blocks (ONE IMAGE each = 1 block/CU), 512 thr (8 waves).
//    Image processed in 8 sections of 4 out-rows (6 staged rows incl. reflect
//    halo). Pipeline with ZERO staging registers:
//      compute(s): [issue global_load_lds prefetch of section s+1 -> fp32
//                   scratch, 24 instrs/wave, no VGPRs] then MFMA tiles.
//      barrier    (compiler's vmcnt(0) drain = exactly the sync we need)
//      convert    (LDS fp32 scratch -> bf16 img[s+1 & 1] + csum/cssq)
//      barrier; stats -> pairs; barrier; next section.
//    Loads fly under the whole MFMA phase; only convert+stats are serial.
//  - Register budget identical to proven v1: bfrag[2][18]=144 AGPR + ~104 VGPR.
//    (Round-1 lesson: +16 vbuf regs spilled bfrag to scratch, +64MB HBM.)
//  - MFMA operands swapped: mfma(Wfrag, patchfrag) -> D^T[row=channel][col=pixel];
//    stores are pixel-contiguous full 64B lines; mean/inv lane-uniform per tile.

#define STRIDE 68            // ushorts per pixel in LDS (136 B -> 2-way banked only)
#define SPIX   192           // 6 rows x 32 cols staged per section
#define SOUT   128           // 4 rows x 32 cols output per section

typedef __attribute__((ext_vector_type(8))) short bf16x8;
typedef __attribute__((ext_vector_type(4))) short bf16x4;
typedef __attribute__((ext_vector_type(4))) float f32x4;

__device__ __forceinline__ unsigned short f2bf(float f) {
    union { float f; unsigned u; } v; v.f = f;
    unsigned r = v.u + 0x7FFFu + ((v.u >> 16) & 1u);   // RNE
    return (unsigned short)(r >> 16);
}
__device__ __forceinline__ unsigned pack2(float a, float b) {
    return (unsigned)f2bf(a) | ((unsigned)f2bf(b) << 16);
}
__device__ __forceinline__ int reflect32(int x) {      // jnp.pad 'reflect', pad=1
    x = (x < 0) ? -x : x;
    return (x > 31) ? (62 - x) : x;
}
__device__ __forceinline__ void gload_lds4(const float* g, float* l) {
    __builtin_amdgcn_global_load_lds(
        (const __attribute__((address_space(1))) unsigned int*)g,
        (__attribute__((address_space(3))) unsigned int*)l,
        4, 0, 0);
}

// ws layout: uint4 wf[4][18][64]  (ntg, ks, lane) -> 8 bf16 frag elements.
// W[k'][o]: o = ntg*16 + (lane&15), k' = ks*32 + (lane>>4)*8 + j,
// with reordered k' = (kh*3+kw)*64 + c  <->  reference k = c*9 + (kh*3+kw).
__global__ void reorder_w_kernel(const float* __restrict__ W, uint4* __restrict__ wf) {
    int idx = blockIdx.x * 256 + threadIdx.x;   // 0..4607
    if (idx >= 4608) return;
    int lane = idx & 63;
    int ks   = (idx >> 6) % 18;
    int ntg  = idx / 1152;
    int quad = lane >> 4;
    int o    = ntg * 16 + (lane & 15);
    unsigned short v[8];
    #pragma unroll
    for (int j = 0; j < 8; ++j) {
        int kp = ks * 32 + quad * 8 + j;
        int c  = kp & 63;
        int s  = kp >> 6;
        v[j] = f2bf(W[(c * 9 + s) * 64 + o]);
    }
    uint4 r;
    r.x = (unsigned)v[0] | ((unsigned)v[1] << 16);
    r.y = (unsigned)v[2] | ((unsigned)v[3] << 16);
    r.z = (unsigned)v[4] | ((unsigned)v[5] << 16);
    r.w = (unsigned)v[6] | ((unsigned)v[7] << 16);
    wf[idx] = r;
}

__global__ __launch_bounds__(512, 2)
void norm_conv_kernel(const float* __restrict__ a,
                      const uint4* __restrict__ wf,
                      float* __restrict__ out) {
    __shared__ unsigned short img[2][SPIX * STRIDE];   // 2 x 26,112 B
    __shared__ float scr[64 * SPIX];                   // 49,152 B fp32 prefetch scratch [c][px]
    __shared__ float csum[SPIX];                       // per staged pixel channel-sum
    __shared__ float cssq[SPIX];                       // per staged pixel channel-sumsq
    __shared__ float pairs[2 * SOUT];                  // (mean, inv) per out pixel of section
    __shared__ float wcs[64];                          // colsum(W_bf16) per out channel

    const int tid  = threadIdx.x;
    const int b    = blockIdx.x;
    const int lane = tid & 63;
    const int wid  = tid >> 6;              // 8 waves
    const int ng   = wid & 1;               // n-half: o in [ng*32, ng*32+32)
    const int wq   = wid >> 1;              // m-group: 2 m-tiles per section
    const int quad = lane >> 4;
    const int mlan = lane & 15;

    const float* Ab = a + (size_t)b * 65536;

    // ---- prefetch of section s into scr (zero registers, async) ----
    auto prefetch = [&](int s) {
        #pragma unroll
        for (int t = 0; t < 24; ++t) {
            int k     = wid * 24 + t;       // 0..191: k = third*64 + c
            int c     = k & 63;
            int third = k >> 6;
            int px    = third * 64 + lane;  // section-local staged pixel
            int grow  = reflect32(4 * s - 1 + (px >> 5));
            gload_lds4(Ab + c * 1024 + grow * 32 + (px & 31),
                       &scr[c * SPIX + third * 64]);   // +lane*4 by HW
        }
    };

    prefetch(0);                            // loads fly while we set up W

    // ---- W fragments: 2 n-tiles x 18 k-steps, held in registers (AGPRs) ----
    bf16x8 bfrag[2][18];
    #pragma unroll
    for (int nt = 0; nt < 2; ++nt) {
        #pragma unroll
        for (int ks = 0; ks < 18; ++ks) {
            union { uint4 u; bf16x8 v; } cvt;
            cvt.u = wf[((ng * 2 + nt) * 18 + ks) * 64 + lane];
            bfrag[nt][ks] = cvt.v;
        }
    }

    // ---- colsum(W_bf16) per lane's two o-columns (exact vs the bf16 GEMM) ----
    float So[2];
    #pragma unroll
    for (int nt = 0; nt < 2; ++nt) {
        float s = 0.f;
        #pragma unroll
        for (int ks = 0; ks < 18; ++ks) {
            #pragma unroll
            for (int j = 0; j < 8; ++j) {
                union { unsigned u; float f; } cv;
                cv.u = ((unsigned)(unsigned short)bfrag[nt][ks][j]) << 16;
                s += cv.f;
            }
        }
        s += __shfl_xor(s, 16, 64);               // sum quads: each quad holds k' subset
        s += __shfl_xor(s, 32, 64);
        So[nt] = s;
    }
    if (wid < 2 && quad == 0) {                   // waves 0,1 cover ng=0,1
        wcs[ng * 32 + mlan]      = So[0];
        wcs[ng * 32 + 16 + mlan] = So[1];
    }

    // ---- convert: scr fp32 -> img[buf] bf16 + csum/cssq (LDS->LDS, cheap) ----
    auto convert = [&](int buf) {
        if (tid < 384) {
            int px = tid >> 1;                    // 0..191
            int h  = tid & 1;                     // channel half
            unsigned short* dst = &img[buf][px * STRIDE];
            const float* sc = &scr[h * 32 * SPIX + px];
            float s = 0.f, q = 0.f;
            #pragma unroll
            for (int c = 0; c < 32; c += 4) {
                float v0 = sc[c * SPIX];
                float v1 = sc[(c + 1) * SPIX];
                float v2 = sc[(c + 2) * SPIX];
                float v3 = sc[(c + 3) * SPIX];
                s += v0 + v1 + v2 + v3;
                q += v0 * v0 + v1 * v1 + v2 * v2 + v3 * v3;
                uint2 pk = { pack2(v0, v1), pack2(v2, v3) };
                *(uint2*)&dst[h * 32 + c] = pk;   // ds_write_b64, ~conflict-free
            }
            s += __shfl_xor(s, 1, 64);            // combine the two halves
            q += __shfl_xor(q, 1, 64);
            if (h == 0) { csum[px] = s; cssq[px] = q; }
        }
    };

    // ---- stats: 3x3 box over channel sums -> (mean, inv) pairs ----
    auto stats = [&]() {
        if (tid < SOUT) {
            int r = tid >> 5, cg = tid & 31;
            float s = 0.f, q = 0.f;
            #pragma unroll
            for (int kh = 0; kh < 3; ++kh) {
                int rb = (r + kh) * 32;           // row reflect baked into staging
                #pragma unroll
                for (int kw = 0; kw < 3; ++kw) {
                    int p = rb + reflect32(cg + kw - 1);
                    s += csum[p];
                    q += cssq[p];
                }
            }
            float mean = s * (1.0f / 576.0f);
            float var  = (q - s * mean) * (1.0f / 575.0f);   // ddof=1
            pairs[tid * 2]     = mean;
            pairs[tid * 2 + 1] = rsqrtf(var);
        }
    };

    __syncthreads();                        // drains prefetch(0) (vmcnt0 at barrier)
    convert(0);
    __syncthreads();
    stats();
    __syncthreads();

    // preload this lane's 8 channel colsums (D^T rows = quad*4+r)
    float so0[4], so1[4];
    #pragma unroll
    for (int r = 0; r < 4; ++r) {
        so0[r] = wcs[ng * 32 + quad * 4 + r];
        so1[r] = wcs[ng * 32 + 16 + quad * 4 + r];
    }

    // ---- main loop over 8 sections ----
    for (int s = 0; s < 8; ++s) {
        if (s < 7) prefetch(s + 1);         // async; lands under this section's MFMA

        const char* imgc = (const char*)img[s & 1];
        float* outB = out + (size_t)b * 65536 + s * SOUT;
        #pragma unroll
        for (int ti = 0; ti < 2; ++ti) {
            const int tt = wq * 2 + ti;           // section-local m-tile 0..7
            const int rl = tt >> 1;               // section-local out row
            const int wl = ((tt & 1) << 4) + mlan;
            const int w0 = reflect32(wl - 1);
            const int w2 = reflect32(wl + 1);
            int base9[9];
            #pragma unroll
            for (int kh = 0; kh < 3; ++kh) {
                int rb = (rl + kh) * 32;
                base9[kh * 3 + 0] = ((rb + w0) * STRIDE + quad * 8) * 2;
                base9[kh * 3 + 1] = ((rb + wl) * STRIDE + quad * 8) * 2;
                base9[kh * 3 + 2] = ((rb + w2) * STRIDE + quad * 8) * 2;
            }
            f32x4 acc0 = {0.f, 0.f, 0.f, 0.f};
            f32x4 acc1 = {0.f, 0.f, 0.f, 0.f};
            #pragma unroll
            for (int ks = 0; ks < 18; ++ks) {
                int off = base9[ks >> 1] + (ks & 1) * 64;       // +32 channels on odd ks
                bf16x4 flo = *(const bf16x4*)(imgc + off);      // ds_read_b64 x2 (8B aligned)
                bf16x4 fhi = *(const bf16x4*)(imgc + off + 8);
                bf16x8 af  = __builtin_shufflevector(flo, fhi, 0, 1, 2, 3, 4, 5, 6, 7);
                acc0 = __builtin_amdgcn_mfma_f32_16x16x32_bf16(bfrag[0][ks], af, acc0, 0, 0, 0);
                acc1 = __builtin_amdgcn_mfma_f32_16x16x32_bf16(bfrag[1][ks], af, acc1, 0, 0, 0);
            }
            // epilogue: D^T -> 16 lanes store 16 consecutive pixels of one channel
            const int lp = tt * 16 + mlan;
            float2 mi = *(const float2*)&pairs[lp * 2];         // (mean, inv)
            float* op = outB + lp;
            #pragma unroll
            for (int r = 0; r < 4; ++r) {
                int oA = ng * 32 + quad * 4 + r;
                op[oA * 1024]        = (acc0[r] - mi.x * so0[r]) * mi.y;
                op[(oA + 16) * 1024] = (acc1[r] - mi.x * so1[r]) * mi.y;
            }
        }

        if (s < 7) {
            __syncthreads();                // drains prefetch(s+1); pairs free
            convert((s + 1) & 1);
            __syncthreads();                // csum/img ready
            stats();
            __syncthreads();                // pairs ready
        }
    }
}

extern "C" void kernel_launch(void* const* d_in, const int* in_sizes, int n_in,
                              void* d_out, int out_size, void* d_ws, size_t ws_size,
                              hipStream_t stream) {
    const float* a = (const float*)d_in[0];
    const float* w = (const float*)d_in[1];
    float* out = (float*)d_out;
    uint4* wf = (uint4*)d_ws;                      // needs 4608*16 = 73,728 B
    reorder_w_kernel<<<dim3(18), dim3(256), 0, stream>>>(w, wf);
    norm_conv_kernel<<<dim3(256), dim3(512), 0, stream>>>(a, (const uint4*)wf, out);
}

// Round 5
// 144.546 us; speedup vs baseline: 1.7313x; 1.7313x over previous
//
#include <hip/hip_runtime.h>

// norm_conv: im2col(3x3 reflect) -> row-normalize -> GEMM[576x64], fused.
// Design: out = (patches@W - mean*colsum(W)) * inv_std.
//  - kernel 1: pre-pack W (fp32->bf16) into per-lane MFMA fragment layout in ws.
//  - kernel 2: 256 blocks (ONE IMAGE each = 1 block/CU), 256 thr (4 waves),
//    PRODUCER/CONSUMER WAVE SPECIALIZATION:
//      waves 0,1 (consumers): hold W frags (144 regs) for one 32-channel half
//        each, run stats + MFMA + epilogue stores. ~230 regs/wave.
//      waves 2,3 (producers): no W frags; stream global->f2bf->LDS + per-pixel
//        channel sums. Producers stage section s+1 WHILE consumers compute
//        section s -> memory and MFMA pipes overlap by construction.
//    __launch_bounds__(256,1): 1 block/CU -> 512-reg/wave budget, NO SPILL
//    (rounds 1-2 lesson: bfrag 144 AGPR + staging regs > 256 cap => scratch).
//  - ALL __syncthreads() AT UNIFORM TOP-LEVEL POINTS (round-3 lesson: barriers
//    inside wave-divergent branches are UB -> possible deadlock/timeout).
//    Divergent producer/consumer work sits BETWEEN uniform barriers.
//  - LDS row RING (10 slots, slot(vrow) = (vrow+1)%10, vrow = -1..32 holds
//    input row reflect32(vrow)): producers append exactly 4 rows per section;
//    consumer section s reads vrows 4s-1..4s+4, producer writes 4s+5..4s+8
//    -> disjoint slot sets. ONE barrier per section.
//  - Row reflect baked into staging; stats per consumer wave (lane-local from
//    csum ring, no cross-wave sync); W colsums distributed via __shfl.
//  - MFMA operands swapped: mfma(Wfrag, patchfrag) -> D^T[row=channel][col=pixel];
//    stores are pixel-contiguous full 64B lines; mean/inv lane-uniform per tile.

#define STRIDE 68            // ushorts per pixel in LDS (136 B -> 2-way banked only)
#define SLOTS  10            // ring row-slots (6 live + 4 being written)

typedef __attribute__((ext_vector_type(8))) short bf16x8;
typedef __attribute__((ext_vector_type(4))) short bf16x4;
typedef __attribute__((ext_vector_type(4))) float f32x4;

__device__ __forceinline__ unsigned short f2bf(float f) {
    union { float f; unsigned u; } v; v.f = f;
    unsigned r = v.u + 0x7FFFu + ((v.u >> 16) & 1u);   // RNE
    return (unsigned short)(r >> 16);
}
__device__ __forceinline__ unsigned pack2(float a, float b) {
    return (unsigned)f2bf(a) | ((unsigned)f2bf(b) << 16);
}
__device__ __forceinline__ int reflect32(int x) {      // jnp.pad 'reflect', pad=1
    x = (x < 0) ? -x : x;
    return (x > 31) ? (62 - x) : x;
}

// ws layout: uint4 wf[4][18][64]  (ntg, ks, lane) -> 8 bf16 frag elements.
// W[k'][o]: o = ntg*16 + (lane&15), k' = ks*32 + (lane>>4)*8 + j,
// with reordered k' = (kh*3+kw)*64 + c  <->  reference k = c*9 + (kh*3+kw).
__global__ void reorder_w_kernel(const float* __restrict__ W, uint4* __restrict__ wf) {
    int idx = blockIdx.x * 256 + threadIdx.x;   // 0..4607
    if (idx >= 4608) return;
    int lane = idx & 63;
    int ks   = (idx >> 6) % 18;
    int ntg  = idx / 1152;
    int quad = lane >> 4;
    int o    = ntg * 16 + (lane & 15);
    unsigned short v[8];
    #pragma unroll
    for (int j = 0; j < 8; ++j) {
        int kp = ks * 32 + quad * 8 + j;
        int c  = kp & 63;
        int s  = kp >> 6;
        v[j] = f2bf(W[(c * 9 + s) * 64 + o]);
    }
    uint4 r;
    r.x = (unsigned)v[0] | ((unsigned)v[1] << 16);
    r.y = (unsigned)v[2] | ((unsigned)v[3] << 16);
    r.z = (unsigned)v[4] | ((unsigned)v[5] << 16);
    r.w = (unsigned)v[6] | ((unsigned)v[7] << 16);
    wf[idx] = r;
}

__global__ __launch_bounds__(256, 1)
void norm_conv_kernel(const float* __restrict__ a,
                      const uint4* __restrict__ wf,
                      float* __restrict__ out) {
    __shared__ unsigned short img[SLOTS * 32 * STRIDE];   // 43,520 B ring
    __shared__ float csum[SLOTS * 32];                    // 1,280 B ring
    __shared__ float cssq[SLOTS * 32];                    // 1,280 B ring
    __shared__ float pairs[2][256];                       // per-consumer-wave (mean,inv)x128

    const int tid  = threadIdx.x;
    const int b    = blockIdx.x;
    const int lane = tid & 63;
    const int wid  = tid >> 6;              // 4 waves
    const int quad = lane >> 4;
    const int mlan = lane & 15;
    const float* Ab = a + (size_t)b * 65536;

    const bool is_prod = (wid >= 2);
    const int  ng = wid;                    // consumer: 32-channel half (0 or 1)
    const int  pl = (wid - 2) * 64 + lane;  // producer: 0..127

    // consumer-only state (producers never touch it; budget 512 regs/wave)
    bf16x8 bfrag[2][18];
    float so0[4], so1[4];

    if (is_prod) {
        // ---- prologue: vrows -1..4 into slots 0..5 (192 px) ----
        for (int i = pl; i < 192; i += 128) {
            int vr  = i >> 5;                    // slot = vr; holds input row reflect(vr-1)
            int col = i & 31;
            const float* src = Ab + reflect32(vr - 1) * 32 + col;
            unsigned short* dst = &img[(vr * 32 + col) * STRIDE];
            float s = 0.f, q = 0.f;
            #pragma unroll 8
            for (int c = 0; c < 64; c += 2) {
                float v0 = src[c * 1024];        // coalesced: lanes -> consecutive cols
                float v1 = src[(c + 1) * 1024];
                s += v0 + v1;
                q += v0 * v0 + v1 * v1;
                *(unsigned*)&dst[c] = pack2(v0, v1);
            }
            csum[vr * 32 + col] = s;
            cssq[vr * 32 + col] = q;
        }
    } else {
        // ---- W fragments for this ng: 2 n-tiles x 18 k-steps (144 regs) ----
        #pragma unroll
        for (int nt = 0; nt < 2; ++nt) {
            #pragma unroll
            for (int ks = 0; ks < 18; ++ks) {
                union { uint4 u; bf16x8 v; } cvt;
                cvt.u = wf[((ng * 2 + nt) * 18 + ks) * 64 + lane];
                bfrag[nt][ks] = cvt.v;
            }
        }
        // colsum(W_bf16): exact vs the bf16 GEMM; distribute via shfl (no LDS)
        float So[2];
        #pragma unroll
        for (int nt = 0; nt < 2; ++nt) {
            float s = 0.f;
            #pragma unroll
            for (int ks = 0; ks < 18; ++ks) {
                #pragma unroll
                for (int j = 0; j < 8; ++j) {
                    union { unsigned u; float f; } cv;
                    cv.u = ((unsigned)(unsigned short)bfrag[nt][ks][j]) << 16;
                    s += cv.f;
                }
            }
            s += __shfl_xor(s, 16, 64);          // sum quad k'-subsets
            s += __shfl_xor(s, 32, 64);
            So[nt] = s;                          // colsum for o = ng*32+nt*16+mlan
        }
        #pragma unroll
        for (int r = 0; r < 4; ++r) {
            so0[r] = __shfl(So[0], quad * 4 + r, 64);
            so1[r] = __shfl(So[1], quad * 4 + r, 64);
        }
    }

    __syncthreads();                        // UNIFORM: prologue staging complete

    const char* imgc = (const char*)img;
    for (int s8 = 0; s8 < 8; ++s8) {
        if (is_prod) {
            // ---- stage 4 rows (vrows 4s+5..4s+8) for section s8+1 ----
            if (s8 < 7) {
                int pb  = (4 * s8 + 6) % 10;     // slot of vrow 4*s8+5
                int dr  = pl >> 5;               // 0..3
                int col = pl & 31;
                int sl  = pb + dr; if (sl >= 10) sl -= 10;
                const float* src = Ab + reflect32(4 * s8 + 5 + dr) * 32 + col;
                unsigned short* dst = &img[(sl * 32 + col) * STRIDE];
                float s = 0.f, q = 0.f;
                #pragma unroll 8
                for (int c = 0; c < 64; c += 2) {
                    float v0 = src[c * 1024];
                    float v1 = src[(c + 1) * 1024];
                    s += v0 + v1;
                    q += v0 * v0 + v1 * v1;
                    *(unsigned*)&dst[c] = pack2(v0, v1);
                }
                csum[sl * 32 + col] = s;
                cssq[sl * 32 + col] = q;
            }
        } else {
            const int bm = (4 * s8) % 10;        // slot of vrow 4*s8-1
            // ---- stats for this section's 128 px (own-wave copy, no sync) ----
            #pragma unroll
            for (int t = 0; t < 2; ++t) {
                int lp = lane + t * 64;
                int rl = lp >> 5, cg = lp & 31;
                float s = 0.f, q = 0.f;
                #pragma unroll
                for (int kh = 0; kh < 3; ++kh) {
                    int sl = bm + rl + kh; if (sl >= 10) sl -= 10;
                    int rb = sl * 32;
                    #pragma unroll
                    for (int kw = 0; kw < 3; ++kw) {
                        int p = rb + reflect32(cg + kw - 1);
                        s += csum[p];
                        q += cssq[p];
                    }
                }
                float mean = s * (1.0f / 576.0f);
                float var  = (q - s * mean) * (1.0f / 575.0f);   // ddof=1
                pairs[ng][lp * 2]     = mean;
                pairs[ng][lp * 2 + 1] = rsqrtf(var);
            }
            // ---- 8 m-tiles x (2 n-tiles via acc0/acc1) ----
            float* outB = out + (size_t)b * 65536 + s8 * 128;
            for (int tt = 0; tt < 8; ++tt) {
                const int rl = tt >> 1;
                const int wl = ((tt & 1) << 4) + mlan;
                const int w0 = reflect32(wl - 1);
                const int w2 = reflect32(wl + 1);
                int base9[9];
                #pragma unroll
                for (int kh = 0; kh < 3; ++kh) {
                    int sl = bm + rl + kh; if (sl >= 10) sl -= 10;
                    int rb = sl * 32;
                    base9[kh * 3 + 0] = ((rb + w0) * STRIDE + quad * 8) * 2;
                    base9[kh * 3 + 1] = ((rb + wl) * STRIDE + quad * 8) * 2;
                    base9[kh * 3 + 2] = ((rb + w2) * STRIDE + quad * 8) * 2;
                }
                f32x4 acc0 = {0.f, 0.f, 0.f, 0.f};
                f32x4 acc1 = {0.f, 0.f, 0.f, 0.f};
                #pragma unroll
                for (int ks = 0; ks < 18; ++ks) {
                    int off = base9[ks >> 1] + (ks & 1) * 64;    // +32 ch on odd ks
                    bf16x4 flo = *(const bf16x4*)(imgc + off);   // ds_read_b64 x2
                    bf16x4 fhi = *(const bf16x4*)(imgc + off + 8);
                    bf16x8 af  = __builtin_shufflevector(flo, fhi, 0, 1, 2, 3, 4, 5, 6, 7);
                    acc0 = __builtin_amdgcn_mfma_f32_16x16x32_bf16(bfrag[0][ks], af, acc0, 0, 0, 0);
                    acc1 = __builtin_amdgcn_mfma_f32_16x16x32_bf16(bfrag[1][ks], af, acc1, 0, 0, 0);
                }
                // epilogue: D^T -> 16 lanes store 16 consecutive px of one channel
                const int lp = tt * 16 + mlan;
                float2 mi = *(const float2*)&pairs[ng][lp * 2];  // (mean, inv)
                float* op = outB + lp;
                #pragma unroll
                for (int r = 0; r < 4; ++r) {
                    int oA = ng * 32 + quad * 4 + r;
                    op[oA * 1024]        = (acc0[r] - mi.x * so0[r]) * mi.y;
                    op[(oA + 16) * 1024] = (acc1[r] - mi.x * so1[r]) * mi.y;
                }
            }
        }
        if (s8 < 7) __syncthreads();        // UNIFORM: section handoff
    }
}

extern "C" void kernel_launch(void* const* d_in, const int* in_sizes, int n_in,
                              void* d_out, int out_size, void* d_ws, size_t ws_size,
                              hipStream_t stream) {
    const float* a = (const float*)d_in[0];
    const float* w = (const float*)d_in[1];
    float* out = (float*)d_out;
    uint4* wf = (uint4*)d_ws;                      // needs 4608*16 = 73,728 B
    reorder_w_kernel<<<dim3(18), dim3(256), 0, stream>>>(w, wf);
    norm_conv_kernel<<<dim3(256), dim3(256), 0, stream>>>(a, (const uint4*)wf, out);
}

// Round 6
// 133.032 us; speedup vs baseline: 1.8812x; 1.0866x over previous
//
#include <hip/hip_runtime.h>

// norm_conv: im2col(3x3 reflect) -> row-normalize -> GEMM[576x64], fused.
// Design: out = (patches@W - mean*colsum(W)) * inv_std.
//  - kernel 1: pre-pack W (fp32->bf16) into per-lane MFMA fragment layout in ws.
//  - kernel 2: 512 blocks (HALF image each => 2 blocks/CU), 256 thr (4 waves),
//    PRODUCER/CONSUMER WAVE SPECIALIZATION:
//      waves 0,1 (consumers): hold W frags (144 regs) for one 32-channel half
//        each, run stats + MFMA + epilogue stores.
//      waves 2,3 (producers): no W frags; stream global->f2bf->LDS + per-pixel
//        channel sums, staging section s+1 WHILE consumers compute section s.
//    Round-4 lesson: at 1 block/CU the single consumer wave per SIMD with 2
//    dependent MFMA chains is LATENCY-bound (60 us). 2 blocks/CU doubles
//    MFMA waves/SIMD (4 indep chains) and de-correlates the two blocks'
//    barriers -> latency hiding both for MFMA and ds_read.
//    __launch_bounds__(256,2): 256 regs/wave cap = exactly the proven
//    112 VGPR + 144 AGPR fit; 2x256 = 512 = per-SIMD register file.
//  - ALL __syncthreads() AT UNIFORM TOP-LEVEL POINTS (round-3 lesson).
//  - LDS row RING (10 slots, slot(r)=(r+1)%10 for block-local row r=-1..16,
//    holding input row reflect32(half*16+r)): producers append exactly 4 rows
//    per section; consumer section s reads local rows 4s-1..4s+4, producer
//    writes 4s+5..4s+8 -> disjoint slot sets. ONE barrier per section.
//  - Row reflect baked into staging; stats per consumer wave (lane-local from
//    csum ring, no cross-wave sync); W colsums distributed via __shfl.
//  - MFMA operands swapped: mfma(Wfrag, patchfrag) -> D^T[row=channel][col=pixel];
//    stores are pixel-contiguous full 64B lines; mean/inv lane-uniform per tile.

#define STRIDE 68            // ushorts per pixel in LDS (136 B -> 2-way banked only)
#define SLOTS  10            // ring row-slots (6 live + 4 being written)

typedef __attribute__((ext_vector_type(8))) short bf16x8;
typedef __attribute__((ext_vector_type(4))) short bf16x4;
typedef __attribute__((ext_vector_type(4))) float f32x4;

__device__ __forceinline__ unsigned short f2bf(float f) {
    union { float f; unsigned u; } v; v.f = f;
    unsigned r = v.u + 0x7FFFu + ((v.u >> 16) & 1u);   // RNE
    return (unsigned short)(r >> 16);
}
__device__ __forceinline__ unsigned pack2(float a, float b) {
    return (unsigned)f2bf(a) | ((unsigned)f2bf(b) << 16);
}
__device__ __forceinline__ int reflect32(int x) {      // jnp.pad 'reflect', pad=1
    x = (x < 0) ? -x : x;
    return (x > 31) ? (62 - x) : x;
}

// ws layout: uint4 wf[4][18][64]  (ntg, ks, lane) -> 8 bf16 frag elements.
// W[k'][o]: o = ntg*16 + (lane&15), k' = ks*32 + (lane>>4)*8 + j,
// with reordered k' = (kh*3+kw)*64 + c  <->  reference k = c*9 + (kh*3+kw).
__global__ void reorder_w_kernel(const float* __restrict__ W, uint4* __restrict__ wf) {
    int idx = blockIdx.x * 256 + threadIdx.x;   // 0..4607
    if (idx >= 4608) return;
    int lane = idx & 63;
    int ks   = (idx >> 6) % 18;
    int ntg  = idx / 1152;
    int quad = lane >> 4;
    int o    = ntg * 16 + (lane & 15);
    unsigned short v[8];
    #pragma unroll
    for (int j = 0; j < 8; ++j) {
        int kp = ks * 32 + quad * 8 + j;
        int c  = kp & 63;
        int s  = kp >> 6;
        v[j] = f2bf(W[(c * 9 + s) * 64 + o]);
    }
    uint4 r;
    r.x = (unsigned)v[0] | ((unsigned)v[1] << 16);
    r.y = (unsigned)v[2] | ((unsigned)v[3] << 16);
    r.z = (unsigned)v[4] | ((unsigned)v[5] << 16);
    r.w = (unsigned)v[6] | ((unsigned)v[7] << 16);
    wf[idx] = r;
}

__global__ __launch_bounds__(256, 2)
void norm_conv_kernel(const float* __restrict__ a,
                      const uint4* __restrict__ wf,
                      float* __restrict__ out) {
    __shared__ unsigned short img[SLOTS * 32 * STRIDE];   // 43,520 B ring
    __shared__ float csum[SLOTS * 32];                    // 1,280 B ring
    __shared__ float cssq[SLOTS * 32];                    // 1,280 B ring
    __shared__ float pairs[2][256];                       // per-consumer-wave (mean,inv)x128

    const int tid   = threadIdx.x;
    const int b     = blockIdx.x >> 1;
    const int half  = blockIdx.x & 1;       // half-image: out rows half*16..half*16+15
    const int rbase = half * 16;
    const int lane  = tid & 63;
    const int wid   = tid >> 6;             // 4 waves
    const int quad  = lane >> 4;
    const int mlan  = lane & 15;
    const float* Ab = a + (size_t)b * 65536;

    const bool is_prod = (wid >= 2);
    const int  ng = wid;                    // consumer: 32-channel half (0 or 1)
    const int  pl = (wid - 2) * 64 + lane;  // producer: 0..127

    // consumer-only state (producers never touch it)
    bf16x8 bfrag[2][18];
    float so0[4], so1[4];

    if (is_prod) {
        // ---- prologue: local rows -1..4 into slots 0..5 (192 px) ----
        for (int i = pl; i < 192; i += 128) {
            int vr  = i >> 5;                    // slot = vr; holds row reflect(rbase+vr-1)
            int col = i & 31;
            const float* src = Ab + reflect32(rbase + vr - 1) * 32 + col;
            unsigned short* dst = &img[(vr * 32 + col) * STRIDE];
            float s = 0.f, q = 0.f;
            #pragma unroll 8
            for (int c = 0; c < 64; c += 2) {
                float v0 = src[c * 1024];        // coalesced: lanes -> consecutive cols
                float v1 = src[(c + 1) * 1024];
                s += v0 + v1;
                q += v0 * v0 + v1 * v1;
                *(unsigned*)&dst[c] = pack2(v0, v1);
            }
            csum[vr * 32 + col] = s;
            cssq[vr * 32 + col] = q;
        }
    } else {
        // ---- W fragments for this ng: 2 n-tiles x 18 k-steps (144 regs) ----
        #pragma unroll
        for (int nt = 0; nt < 2; ++nt) {
            #pragma unroll
            for (int ks = 0; ks < 18; ++ks) {
                union { uint4 u; bf16x8 v; } cvt;
                cvt.u = wf[((ng * 2 + nt) * 18 + ks) * 64 + lane];
                bfrag[nt][ks] = cvt.v;
            }
        }
        // colsum(W_bf16): exact vs the bf16 GEMM; distribute via shfl (no LDS)
        float So[2];
        #pragma unroll
        for (int nt = 0; nt < 2; ++nt) {
            float s = 0.f;
            #pragma unroll
            for (int ks = 0; ks < 18; ++ks) {
                #pragma unroll
                for (int j = 0; j < 8; ++j) {
                    union { unsigned u; float f; } cv;
                    cv.u = ((unsigned)(unsigned short)bfrag[nt][ks][j]) << 16;
                    s += cv.f;
                }
            }
            s += __shfl_xor(s, 16, 64);          // sum quad k'-subsets
            s += __shfl_xor(s, 32, 64);
            So[nt] = s;                          // colsum for o = ng*32+nt*16+mlan
        }
        #pragma unroll
        for (int r = 0; r < 4; ++r) {
            so0[r] = __shfl(So[0], quad * 4 + r, 64);
            so1[r] = __shfl(So[1], quad * 4 + r, 64);
        }
    }

    __syncthreads();                        // UNIFORM: prologue staging complete

    const char* imgc = (const char*)img;
    for (int s8 = 0; s8 < 4; ++s8) {
        if (is_prod) {
            // ---- stage 4 rows (local rows 4s+5..4s+8) for section s8+1 ----
            if (s8 < 3) {
                int pb  = (4 * s8 + 6) % 10;     // slot of local row 4*s8+5
                int dr  = pl >> 5;               // 0..3
                int col = pl & 31;
                int sl  = pb + dr; if (sl >= 10) sl -= 10;
                const float* src = Ab + reflect32(rbase + 4 * s8 + 5 + dr) * 32 + col;
                unsigned short* dst = &img[(sl * 32 + col) * STRIDE];
                float s = 0.f, q = 0.f;
                #pragma unroll 8
                for (int c = 0; c < 64; c += 2) {
                    float v0 = src[c * 1024];
                    float v1 = src[(c + 1) * 1024];
                    s += v0 + v1;
                    q += v0 * v0 + v1 * v1;
                    *(unsigned*)&dst[c] = pack2(v0, v1);
                }
                csum[sl * 32 + col] = s;
                cssq[sl * 32 + col] = q;
            }
        } else {
            const int bm = (4 * s8) % 10;        // slot of local row 4*s8-1
            // ---- stats for this section's 128 px (own-wave copy, no sync) ----
            #pragma unroll
            for (int t = 0; t < 2; ++t) {
                int lp = lane + t * 64;
                int rl = lp >> 5, cg = lp & 31;
                float s = 0.f, q = 0.f;
                #pragma unroll
                for (int kh = 0; kh < 3; ++kh) {
                    int sl = bm + rl + kh; if (sl >= 10) sl -= 10;
                    int rb = sl * 32;
                    #pragma unroll
                    for (int kw = 0; kw < 3; ++kw) {
                        int p = rb + reflect32(cg + kw - 1);
                        s += csum[p];
                        q += cssq[p];
                    }
                }
                float mean = s * (1.0f / 576.0f);
                float var  = (q - s * mean) * (1.0f / 575.0f);   // ddof=1
                pairs[ng][lp * 2]     = mean;
                pairs[ng][lp * 2 + 1] = rsqrtf(var);
            }
            // ---- 8 m-tiles x (2 n-tiles via acc0/acc1) ----
            float* outB = out + (size_t)b * 65536 + half * 512 + s8 * 128;
            for (int tt = 0; tt < 8; ++tt) {
                const int rl = tt >> 1;
                const int wl = ((tt & 1) << 4) + mlan;
                const int w0 = reflect32(wl - 1);
                const int w2 = reflect32(wl + 1);
                int base9[9];
                #pragma unroll
                for (int kh = 0; kh < 3; ++kh) {
                    int sl = bm + rl + kh; if (sl >= 10) sl -= 10;
                    int rb = sl * 32;
                    base9[kh * 3 + 0] = ((rb + w0) * STRIDE + quad * 8) * 2;
                    base9[kh * 3 + 1] = ((rb + wl) * STRIDE + quad * 8) * 2;
                    base9[kh * 3 + 2] = ((rb + w2) * STRIDE + quad * 8) * 2;
                }
                f32x4 acc0 = {0.f, 0.f, 0.f, 0.f};
                f32x4 acc1 = {0.f, 0.f, 0.f, 0.f};
                #pragma unroll
                for (int ks = 0; ks < 18; ++ks) {
                    int off = base9[ks >> 1] + (ks & 1) * 64;    // +32 ch on odd ks
                    bf16x4 flo = *(const bf16x4*)(imgc + off);   // ds_read_b64 x2
                    bf16x4 fhi = *(const bf16x4*)(imgc + off + 8);
                    bf16x8 af  = __builtin_shufflevector(flo, fhi, 0, 1, 2, 3, 4, 5, 6, 7);
                    acc0 = __builtin_amdgcn_mfma_f32_16x16x32_bf16(bfrag[0][ks], af, acc0, 0, 0, 0);
                    acc1 = __builtin_amdgcn_mfma_f32_16x16x32_bf16(bfrag[1][ks], af, acc1, 0, 0, 0);
                }
                // epilogue: D^T -> 16 lanes store 16 consecutive px of one channel
                const int lp = tt * 16 + mlan;
                float2 mi = *(const float2*)&pairs[ng][lp * 2];  // (mean, inv)
                float* op = outB + lp;
                #pragma unroll
                for (int r = 0; r < 4; ++r) {
                    int oA = ng * 32 + quad * 4 + r;
                    op[oA * 1024]        = (acc0[r] - mi.x * so0[r]) * mi.y;
                    op[(oA + 16) * 1024] = (acc1[r] - mi.x * so1[r]) * mi.y;
                }
            }
        }
        if (s8 < 3) __syncthreads();        // UNIFORM: section handoff
    }
}

extern "C" void kernel_launch(void* const* d_in, const int* in_sizes, int n_in,
                              void* d_out, int out_size, void* d_ws, size_t ws_size,
                              hipStream_t stream) {
    const float* a = (const float*)d_in[0];
    const float* w = (const float*)d_in[1];
    float* out = (float*)d_out;
    uint4* wf = (uint4*)d_ws;                      // needs 4608*16 = 73,728 B
    reorder_w_kernel<<<dim3(18), dim3(256), 0, stream>>>(w, wf);
    norm_conv_kernel<<<dim3(512), dim3(256), 0, stream>>>(a, (const uint4*)wf, out);
}